// Round 5
// baseline (384.923 us; speedup 1.0000x reference)
//
#include <hip/hip_runtime.h>
#include <hip/hip_bf16.h>

// ModulatedConv2d: B=8, Cin=Cout=512, H=W=64, K=3, style_dim=512
// bf16 implicit GEMM per batch: out[o][p] = sum_k W'[o][k] X[k][p].

using Acc4  = __attribute__((ext_vector_type(4))) float;
using Frag8 = __attribute__((ext_vector_type(8))) short;   // 8 bf16 (4 VGPRs)

__device__ __forceinline__ void load_lds16(const void* g, void* l) {
  __builtin_amdgcn_global_load_lds((const __attribute__((address_space(1))) void*)g,
                                   (__attribute__((address_space(3))) void*)l, 16, 0, 0);
}

// ---------------- kernel 1: s[b][c] = dot(style[b], mod_w[c]) -------------
// s is parked in d_out (conv_kernel fully overwrites d_out afterwards).
__global__ __launch_bounds__(256) void style_kernel(
    const float* __restrict__ style,   // [8][512]
    const float* __restrict__ mod_w,   // [512][512]
    float* __restrict__ s_out) {       // [8][512] (in d_out)
  const int b    = blockIdx.y;
  const int wid  = threadIdx.x >> 6;
  const int lane = threadIdx.x & 63;
  const int c    = blockIdx.x * 4 + wid;
  const float4* mw = (const float4*)(mod_w + (size_t)c * 512);
  const float4* st = (const float4*)(style + (size_t)b * 512);
  float sum = 0.f;
#pragma unroll
  for (int i = 0; i < 2; ++i) {
    float4 m = mw[lane + i * 64];
    float4 s = st[lane + i * 64];
    sum += m.x * s.x + m.y * s.y + m.z * s.z + m.w * s.w;
  }
#pragma unroll
  for (int off = 32; off > 0; off >>= 1) sum += __shfl_xor(sum, off, 64);
  if (lane == 0) s_out[b * 512 + c] = sum;
}

// ---------------- kernel 2: fused prep (modwrite + transpose) -------------
// blocks [0,4096): modwrite, one per (o,b). wout: [b][tap][o][c] bf16.
// blocks [4096,8192): NCHW fp32 -> NHWC bf16 transpose tiles.
__global__ __launch_bounds__(256) void prep_kernel(
    const float* __restrict__ weight,  // [512][512][3][3] ([o][c][ky][kx])
    const float* __restrict__ s_in,    // [8][512] (in d_out)
    const float* __restrict__ x,       // [8][512][4096]
    __hip_bfloat16* __restrict__ xbf,  // [8][4096][512]
    __hip_bfloat16* __restrict__ wout) {
  __shared__ __align__(16) char plds[20608];
  const int bid = blockIdx.x;
  const int tid = threadIdx.x;

  if (bid < 4096) {
    // ---- modwrite role ----
    float* ws    = (float*)plds;            // [4608]
    float* s_lds = (float*)(plds + 18432);  // [512]
    float* red   = (float*)(plds + 20480);  // [4]
    float* smult = (float*)(plds + 20496);
    const int o = bid & 511;
    const int b = bid >> 9;
    const int lane = tid & 63;
    const int wid  = tid >> 6;

    for (int i = tid; i < 512; i += 256) s_lds[i] = s_in[b * 512 + i];
    __syncthreads();

    const float2* w2 = (const float2*)(weight + (size_t)o * 4608);
    float sum = 0.f;
#pragma unroll
    for (int i = 0; i < 9; ++i) {
      int idx = i * 256 + tid;          // float2 index 0..2303
      float2 v = w2[idx];
      int e0 = idx * 2;
      int c0 = (e0 * 7282) >> 16;       // e/9 for e<4608
      int c1 = ((e0 + 1) * 7282) >> 16;
      float a  = v.x * s_lds[c0];
      float bb = v.y * s_lds[c1];
      ws[e0] = a; ws[e0 + 1] = bb;
      sum += a * a + bb * bb;
    }
#pragma unroll
    for (int off = 32; off > 0; off >>= 1) sum += __shfl_xor(sum, off, 64);
    if (lane == 0) red[wid] = sum;
    __syncthreads();
    if (tid == 0) {
      const float scale = 1.4731391e-2f;  // 1/sqrt(512*9)
      float t = red[0] + red[1] + red[2] + red[3];
      *smult = scale * rsqrtf(t * scale * scale + 1e-8f);
    }
    __syncthreads();
    const float mult = *smult;
    const int c = tid * 2;
#pragma unroll
    for (int t = 0; t < 9; ++t) {
      __hip_bfloat16* orow = wout + (((size_t)b * 9 + t) * 512 + o) * 512;
      __hip_bfloat16 h0 = __float2bfloat16(ws[c * 9 + t] * mult);
      __hip_bfloat16 h1 = __float2bfloat16(ws[(c + 1) * 9 + t] * mult);
      ushort2 pk = { *(unsigned short*)&h0, *(unsigned short*)&h1 };
      *(ushort2*)(orow + c) = pk;       // 4B/lane coalesced
    }
  } else {
    // ---- transpose role ----
    float (*t_lds)[65] = (float(*)[65])plds;   // [64][65]
    const int idx = bid - 4096;
    const int pt = idx & 63;
    const int ct = (idx >> 6) & 7;
    const int b  = idx >> 9;
    const int l16 = tid & 15, g16 = tid >> 4;
    const int c0 = ct * 64, p0 = pt * 64;
    const float* xb = x + ((size_t)b * 512 + c0) * 4096 + p0;
#pragma unroll
    for (int i = 0; i < 4; ++i) {
      int c = i * 16 + g16;
      float4 v = *(const float4*)(xb + (size_t)c * 4096 + l16 * 4);
      t_lds[c][l16 * 4 + 0] = v.x; t_lds[c][l16 * 4 + 1] = v.y;
      t_lds[c][l16 * 4 + 2] = v.z; t_lds[c][l16 * 4 + 3] = v.w;
    }
    __syncthreads();
    __hip_bfloat16* ob = xbf + ((size_t)b * 4096 + p0) * 512 + c0;
#pragma unroll
    for (int i = 0; i < 4; ++i) {
      int p = i * 16 + g16;
      int c = l16 * 4;
      __hip_bfloat16 h0 = __float2bfloat16(t_lds[c + 0][p]);
      __hip_bfloat16 h1 = __float2bfloat16(t_lds[c + 1][p]);
      __hip_bfloat16 h2 = __float2bfloat16(t_lds[c + 2][p]);
      __hip_bfloat16 h3 = __float2bfloat16(t_lds[c + 3][p]);
      ushort4 pk = { *(unsigned short*)&h0, *(unsigned short*)&h1,
                     *(unsigned short*)&h2, *(unsigned short*)&h3 };
      *(ushort4*)(ob + (size_t)p * 512 + c) = pk;   // 8B/lane coalesced
    }
  }
}

// ---------------- kernel 3: implicit-GEMM conv ----------------------------
// Block: 256 thr (4 waves, 2x2), tile BM=128 (o) x BN=256 (4 image rows).
// Per-wave output 64 o x 128 p (acc 4x8) -> 43.7 FLOP per LDS byte.
// LDS map: X [384 pos(6 rows)][64 c]  @ 0      .. 49151  (48KB)
//          W buf0 [128 o][64 c]       @ 49152  .. 65535  (16KB)
//          W buf1 [128 o][64 c]       @ 65536  .. 81919  (16KB)
// (round-4 bug: `woff ^= 16384` from 0xC000 landed at 0x8000 = inside X.
//  Fixed with explicit wsel -> W_OFF + wsel*16384.)
// XOR swizzle on 16B chunks: slot(row, ch) holds global chunk (row, ch^(row&7)).
#define X_OFF 0
#define W_OFF 49152

__global__ __launch_bounds__(256, 2) void conv_kernel(
    const __hip_bfloat16* __restrict__ xbf,   // [8][4096][512]
    const __hip_bfloat16* __restrict__ wmod,  // [8][9][512][512]
    float* __restrict__ out) {                // [8][512][4096]
  __shared__ __align__(16) char lds[81920];
  // XCD swizzle: 512 blocks, XCD x owns nid [x*64, x*64+64) == sample b=x.
  const int bid  = blockIdx.x;
  const int nid  = (bid & 7) * 64 + (bid >> 3);
  const int ptile = nid & 15;        // 16 ptiles x 4 rows
  const int otile = (nid >> 4) & 3;
  const int b     = nid >> 6;
  const int tid  = threadIdx.x;
  const int lane = tid & 63;
  const int wid  = tid >> 6;
  const int wr   = wid >> 1, wc = wid & 1;
  const int y0   = ptile * 4;
  const int o0   = otile * 128;

  Acc4 acc[4][8] = {};
  const Frag8 zfrag = {0, 0, 0, 0, 0, 0, 0, 0};

  auto stageX = [&](int cs) {
    const int c0 = cs * 64;
#pragma unroll
    for (int i = 0; i < 12; ++i) {
      int chunk = i * 256 + tid;
      int pos = chunk >> 3, ch = chunk & 7;   // pos 0..383 (6 rows)
      int gy  = min(63, max(0, y0 - 1 + (pos >> 6)));
      int gx  = pos & 63;
      int sch = ch ^ (pos & 7);
      load_lds16(xbf + (((size_t)b * 4096 + gy * 64 + gx) * 512 + c0 + sch * 8),
                 lds + X_OFF + i * 4096 + wid * 1024);
    }
  };
  auto stageW = [&](int cs, int tap, int dst) {
    const int c0 = cs * 64;
#pragma unroll
    for (int i = 0; i < 4; ++i) {
      int chunk = i * 256 + tid;
      int o = chunk >> 3, ch = chunk & 7;
      int sch = ch ^ (o & 7);
      load_lds16(wmod + ((((size_t)b * 9 + tap) * 512 + o0 + o) * 512 + c0 + sch * 8),
                 lds + dst + i * 4096 + wid * 1024);
    }
  };

  int wsel = 0;                       // compute buffer = W_OFF + wsel*16384
  stageX(0);
  stageW(0, 0, W_OFF);
  asm volatile("s_waitcnt vmcnt(0)" ::: "memory");
  __builtin_amdgcn_s_barrier();

  for (int cs = 0; cs < 8; ++cs) {
#pragma unroll
    for (int tap = 0; tap < 9; ++tap) {
      const int woff  = W_OFF + (wsel << 14);
      const int wnext = W_OFF + ((wsel ^ 1) << 14);
      // 1. issue next W-tap stage into the other buffer
      if (tap < 8)           stageW(cs, tap + 1, wnext);
      else if (cs < 7)       stageW(cs + 1, 0, wnext);

      // 2. compute current tap from W[woff] + X
      const int ky = tap / 3;
      const int kx = tap % 3;
      int  psv[8];
      bool valid[8];
#pragma unroll
      for (int n = 0; n < 8; ++n) {
        int plocal = wc * 128 + n * 16 + (lane & 15);  // 0..255
        int row  = plocal >> 6;                        // 0..3
        int xx   = plocal & 63;
        int sx   = xx + kx - 1;
        int sy   = y0 + row + ky - 1;
        valid[n] = ((unsigned)sx < 64u) && ((unsigned)sy < 64u);
        psv[n]   = (row + ky) * 64 + (sx & 63);        // 0..383
      }
#pragma unroll
      for (int ks = 0; ks < 2; ++ks) {
        Frag8 af[4], bfr[8];
        const int chq = ks * 4 + (lane >> 4);
#pragma unroll
        for (int m = 0; m < 4; ++m) {
          int o = wr * 64 + m * 16 + (lane & 15);
          af[m] = *(const Frag8*)(lds + woff + o * 128 + ((chq ^ (o & 7)) << 4));
        }
#pragma unroll
        for (int n = 0; n < 8; ++n) {
          int ps = psv[n];
          Frag8 v = *(const Frag8*)(lds + X_OFF + ps * 128 + ((chq ^ (ps & 7)) << 4));
          bfr[n] = valid[n] ? v : zfrag;
        }
        __builtin_amdgcn_s_setprio(1);
#pragma unroll
        for (int m = 0; m < 4; ++m)
#pragma unroll
          for (int n = 0; n < 8; ++n)
            acc[m][n] = __builtin_amdgcn_mfma_f32_16x16x32_bf16(af[m], bfr[n], acc[m][n], 0, 0, 0);
        __builtin_amdgcn_s_setprio(0);
      }

      // 3. end-of-tap sync
      if (tap < 8) {
        asm volatile("s_waitcnt vmcnt(0)" ::: "memory");
        __builtin_amdgcn_s_barrier();
      } else {
        __builtin_amdgcn_s_barrier();          // all waves done reading X[cs]
        if (cs < 7) stageX(cs + 1);
        asm volatile("s_waitcnt vmcnt(0)" ::: "memory");
        __builtin_amdgcn_s_barrier();
      }
      wsel ^= 1;
    }
  }

  // epilogue: D layout col=lane&15 (p), row=(lane>>4)*4+j (o)
#pragma unroll
  for (int m = 0; m < 4; ++m) {
    int o = o0 + wr * 64 + m * 16 + ((lane >> 4) << 2);
#pragma unroll
    for (int n = 0; n < 8; ++n) {
      int p = ptile * 256 + wc * 128 + n * 16 + (lane & 15);
      float* dst = out + ((size_t)b * 512 + o) * 4096 + p;
#pragma unroll
      for (int j = 0; j < 4; ++j) dst[(size_t)j * 4096] = acc[m][n][j];
    }
  }
}

// ---------------- launch --------------------------------------------------
extern "C" void kernel_launch(void* const* d_in, const int* in_sizes, int n_in,
                              void* d_out, int out_size, void* d_ws, size_t ws_size,
                              hipStream_t stream) {
  const float* x      = (const float*)d_in[0];
  const float* style  = (const float*)d_in[1];
  const float* weight = (const float*)d_in[2];
  const float* mod_w  = (const float*)d_in[3];
  float* out = (float*)d_out;

  __hip_bfloat16* xbf  = (__hip_bfloat16*)d_ws;                       // 33.55 MB
  __hip_bfloat16* wmod = (__hip_bfloat16*)((char*)d_ws + (size_t)8 * 4096 * 512 * 2);
  // s[8][512] is parked at the START of d_out: prep_kernel consumes it and
  // conv_kernel (which runs after) fully overwrites d_out.
  float* s_buf = (float*)d_out;

  style_kernel<<<dim3(128, 8), 256, 0, stream>>>(style, mod_w, s_buf);
  prep_kernel <<<dim3(8192), 256, 0, stream>>>(weight, s_buf, x, xbf, wmod);
  conv_kernel <<<dim3(512), 256, 0, stream>>>(xbf, wmod, out);
}

// Round 6
// 265.318 us; speedup vs baseline: 1.4508x; 1.4508x over previous
//
#include <hip/hip_runtime.h>
#include <hip/hip_bf16.h>

// ModulatedConv2d: B=8, Cin=Cout=512, H=W=64, K=3, style_dim=512
// bf16 implicit GEMM per batch: out[o][p] = sum_k W'[o][k] X[k][p].

using Acc4  = __attribute__((ext_vector_type(4))) float;
using Frag8 = __attribute__((ext_vector_type(8))) short;   // 8 bf16 (4 VGPRs)

__device__ __forceinline__ void load_lds16(const void* g, void* l) {
  __builtin_amdgcn_global_load_lds((const __attribute__((address_space(1))) void*)g,
                                   (__attribute__((address_space(3))) void*)l, 16, 0, 0);
}

// ---------------- kernel 1: s[b][c] = dot(style[b], mod_w[c]) -------------
// s is parked in d_out (conv_kernel fully overwrites d_out afterwards).
__global__ __launch_bounds__(256) void style_kernel(
    const float* __restrict__ style,   // [8][512]
    const float* __restrict__ mod_w,   // [512][512]
    float* __restrict__ s_out) {       // [8][512] (in d_out)
  const int b    = blockIdx.y;
  const int wid  = threadIdx.x >> 6;
  const int lane = threadIdx.x & 63;
  const int c    = blockIdx.x * 4 + wid;
  const float4* mw = (const float4*)(mod_w + (size_t)c * 512);
  const float4* st = (const float4*)(style + (size_t)b * 512);
  float sum = 0.f;
#pragma unroll
  for (int i = 0; i < 2; ++i) {
    float4 m = mw[lane + i * 64];
    float4 s = st[lane + i * 64];
    sum += m.x * s.x + m.y * s.y + m.z * s.z + m.w * s.w;
  }
#pragma unroll
  for (int off = 32; off > 0; off >>= 1) sum += __shfl_xor(sum, off, 64);
  if (lane == 0) s_out[b * 512 + c] = sum;
}

// ---------------- kernel 2: fused prep (modwrite + transpose) -------------
// blocks [0,512): modwrite, one per o, ALL 8 b (weight row read once).
// blocks [512,4608): NCHW fp32 -> NHWC bf16 transpose tiles.
__global__ __launch_bounds__(256) void prep_kernel(
    const float* __restrict__ weight,  // [512][512][3][3] ([o][c][ky][kx])
    const float* __restrict__ s_in,    // [8][512] (in d_out)
    const float* __restrict__ x,       // [8][512][4096]
    __hip_bfloat16* __restrict__ xbf,  // [8][4096][512]
    __hip_bfloat16* __restrict__ wout) {
  __shared__ __align__(16) char plds[35008];
  const int bid = blockIdx.x;
  const int tid = threadIdx.x;

  if (bid < 512) {
    // ---- modwrite role: one o, all 8 b ----
    float* wr   = (float*)plds;            // [4608]  modulated-src weights
    float* sall = (float*)(plds + 18432);  // [4096]  s for all 8 b
    float* red  = (float*)(plds + 34816);  // [4][8]
    float* mlt  = (float*)(plds + 34944);  // [8]
    const int o    = bid;
    const int lane = tid & 63;
    const int wid  = tid >> 6;

    for (int i = tid; i < 4096; i += 256) sall[i] = s_in[i];

    const float2* w2 = (const float2*)(weight + (size_t)o * 4608);
    float2 myw[9];
    int    ce0[9], ce1[9];
#pragma unroll
    for (int i = 0; i < 9; ++i) {
      int idx = i * 256 + tid;          // float2 index 0..2303
      myw[i] = w2[idx];
      int e0 = idx * 2;
      ce0[i] = (e0 * 7282) >> 16;       // e/9 for e<4608
      ce1[i] = ((e0 + 1) * 7282) >> 16;
      wr[e0] = myw[i].x; wr[e0 + 1] = myw[i].y;
    }
    __syncthreads();

    float s8[8];
#pragma unroll
    for (int b = 0; b < 8; ++b) {
      float sum = 0.f;
#pragma unroll
      for (int i = 0; i < 9; ++i) {
        float a  = myw[i].x * sall[b * 512 + ce0[i]];
        float bb = myw[i].y * sall[b * 512 + ce1[i]];
        sum += a * a + bb * bb;
      }
      s8[b] = sum;
    }
#pragma unroll
    for (int b = 0; b < 8; ++b) {
#pragma unroll
      for (int off = 32; off > 0; off >>= 1) s8[b] += __shfl_xor(s8[b], off, 64);
      if (lane == 0) red[wid * 8 + b] = s8[b];
    }
    __syncthreads();
    if (tid < 8) {
      const float scale = 1.4731391e-2f;  // 1/sqrt(512*9)
      float t = red[tid] + red[8 + tid] + red[16 + tid] + red[24 + tid];
      mlt[tid] = scale * rsqrtf(t * scale * scale + 1e-8f);
    }
    __syncthreads();

    const int c = tid * 2;
#pragma unroll
    for (int b = 0; b < 8; ++b) {
      const float mult = mlt[b];
      const float sc0 = sall[b * 512 + c]     * mult;
      const float sc1 = sall[b * 512 + c + 1] * mult;
#pragma unroll
      for (int t = 0; t < 9; ++t) {
        __hip_bfloat16* orow = wout + (((size_t)b * 9 + t) * 512 + o) * 512;
        __hip_bfloat16 h0 = __float2bfloat16(wr[c * 9 + t] * sc0);
        __hip_bfloat16 h1 = __float2bfloat16(wr[(c + 1) * 9 + t] * sc1);
        ushort2 pk = { *(unsigned short*)&h0, *(unsigned short*)&h1 };
        *(ushort2*)(orow + c) = pk;     // 4B/lane coalesced
      }
    }
  } else {
    // ---- transpose role ----
    float (*t_lds)[65] = (float(*)[65])plds;   // [64][65]
    const int idx = bid - 512;
    const int pt = idx & 63;
    const int ct = (idx >> 6) & 7;
    const int b  = idx >> 9;
    const int l16 = tid & 15, g16 = tid >> 4;
    const int c0 = ct * 64, p0 = pt * 64;
    const float* xb = x + ((size_t)b * 512 + c0) * 4096 + p0;
#pragma unroll
    for (int i = 0; i < 4; ++i) {
      int c = i * 16 + g16;
      float4 v = *(const float4*)(xb + (size_t)c * 4096 + l16 * 4);
      t_lds[c][l16 * 4 + 0] = v.x; t_lds[c][l16 * 4 + 1] = v.y;
      t_lds[c][l16 * 4 + 2] = v.z; t_lds[c][l16 * 4 + 3] = v.w;
    }
    __syncthreads();
    __hip_bfloat16* ob = xbf + ((size_t)b * 4096 + p0) * 512 + c0;
#pragma unroll
    for (int i = 0; i < 4; ++i) {
      int p = i * 16 + g16;
      int c = l16 * 4;
      __hip_bfloat16 h0 = __float2bfloat16(t_lds[c + 0][p]);
      __hip_bfloat16 h1 = __float2bfloat16(t_lds[c + 1][p]);
      __hip_bfloat16 h2 = __float2bfloat16(t_lds[c + 2][p]);
      __hip_bfloat16 h3 = __float2bfloat16(t_lds[c + 3][p]);
      ushort4 pk = { *(unsigned short*)&h0, *(unsigned short*)&h1,
                     *(unsigned short*)&h2, *(unsigned short*)&h3 };
      *(ushort4*)(ob + (size_t)p * 512 + c) = pk;   // 8B/lane coalesced
    }
  }
}

// ---------------- kernel 3: implicit-GEMM conv ----------------------------
// Round-3 tile (verified 131us, 124 VGPR, no spill): BM=128 (o) x BN=128
// (2 image rows), 4 waves 2x2, acc 4x4 per wave.
// NEW: W TRIPLE-buffer + counted vmcnt (T4): per tap issue W[T+2], compute T,
// wait vmcnt(4) (= W[T+1] landed; W[T+2] stays in flight across the barrier).
// Buffer index = tap%3 (9 taps = 0 mod 3 -> compile-time per unrolled tap).
// Full vmcnt(0) drain only at the 8 cs boundaries (X restage).
// LDS map: X [256 pos(4 rows)][64 c] @ 0..32767 (32KB)
//          W buf k @ 32768 + k*16384, k=0,1,2 (48KB) -> total 80KB, 2 blk/CU.
// XOR swizzle on 16B chunks: slot(row, ch) holds global chunk (row, ch^(row&7)).
#define X_OFF 0
#define W_OFF 32768

__global__ __launch_bounds__(256, 2) void conv_kernel(
    const __hip_bfloat16* __restrict__ xbf,   // [8][4096][512]
    const __hip_bfloat16* __restrict__ wmod,  // [8][9][512][512]
    float* __restrict__ out) {                // [8][512][4096]
  __shared__ __align__(16) char lds[81920];
  // XCD swizzle: 1024 blocks, XCD x owns nid [x*128, x*128+128) == sample b=x.
  const int bid  = blockIdx.x;
  const int nid  = (bid & 7) * 128 + (bid >> 3);
  const int ptile = nid & 31;        // 32 ptiles x 2 rows
  const int otile = (nid >> 5) & 3;
  const int b     = nid >> 7;
  const int tid  = threadIdx.x;
  const int lane = tid & 63;
  const int wid  = tid >> 6;
  const int wr   = wid >> 1, wc = wid & 1;
  const int y0   = ptile * 2;
  const int o0   = otile * 128;

  Acc4 acc[4][4] = {};
  const Frag8 zfrag = {0, 0, 0, 0, 0, 0, 0, 0};

  auto stageX = [&](int cs) {
    const int c0 = cs * 64;
#pragma unroll
    for (int i = 0; i < 8; ++i) {
      int chunk = i * 256 + tid;
      int pos = chunk >> 3, ch = chunk & 7;   // pos 0..255 (4 rows y0-1..y0+2)
      int gy  = min(63, max(0, y0 - 1 + (pos >> 6)));
      int gx  = pos & 63;
      int sch = ch ^ (pos & 7);
      load_lds16(xbf + (((size_t)b * 4096 + gy * 64 + gx) * 512 + c0 + sch * 8),
                 lds + X_OFF + i * 4096 + wid * 1024);
    }
  };
  auto stageW = [&](int cs, int tap, int dst) {
    const int c0 = cs * 64;
#pragma unroll
    for (int i = 0; i < 4; ++i) {
      int chunk = i * 256 + tid;
      int o = chunk >> 3, ch = chunk & 7;
      int sch = ch ^ (o & 7);
      load_lds16(wmod + ((((size_t)b * 9 + tap) * 512 + o0 + o) * 512 + c0 + sch * 8),
                 lds + dst + i * 4096 + wid * 1024);
    }
  };

  // prologue: X(8) + W[0](4) + W[1](4) issued; wait 12 oldest (X, W0) done.
  stageX(0);
  stageW(0, 0, W_OFF);               // flat T=0 -> buf 0
  stageW(0, 1, W_OFF + 16384);       // flat T=1 -> buf 1
  asm volatile("s_waitcnt vmcnt(4)" ::: "memory");
  __builtin_amdgcn_s_barrier();

  for (int cs = 0; cs < 8; ++cs) {
#pragma unroll
    for (int tap = 0; tap < 9; ++tap) {
      // 1. issue W stage for flat index T+2 into buf (tap+2)%3
      {
        int tap2 = tap + 2, cs2 = cs;
        if (tap2 >= 9) { tap2 -= 9; cs2 += 1; }
        if (cs2 < 8) stageW(cs2, tap2, W_OFF + (((tap + 2) % 3) << 14));
      }

      // 2. compute current tap from Wbuf[tap%3] + X
      const int woff = W_OFF + ((tap % 3) << 14);
      const int ky = tap / 3;
      const int kx = tap % 3;
      int  psv[4];
      bool valid[4];
#pragma unroll
      for (int n = 0; n < 4; ++n) {
        int plocal = wc * 64 + n * 16 + (lane & 15);
        int yrel = plocal >> 6;
        int xx   = plocal & 63;
        int sx   = xx + kx - 1;
        int sy   = y0 + yrel + ky - 1;
        valid[n] = ((unsigned)sx < 64u) && ((unsigned)sy < 64u);
        psv[n]   = (((yrel + ky) * 64 + sx) & 255);
      }
#pragma unroll
      for (int ks = 0; ks < 2; ++ks) {
        Frag8 af[4], bfr[4];
        const int chq = ks * 4 + (lane >> 4);
#pragma unroll
        for (int m = 0; m < 4; ++m) {
          int o = wr * 64 + m * 16 + (lane & 15);
          af[m] = *(const Frag8*)(lds + woff + o * 128 + ((chq ^ (o & 7)) << 4));
        }
#pragma unroll
        for (int n = 0; n < 4; ++n) {
          int ps = psv[n];
          Frag8 v = *(const Frag8*)(lds + X_OFF + ps * 128 + ((chq ^ (ps & 7)) << 4));
          bfr[n] = valid[n] ? v : zfrag;
        }
        __builtin_amdgcn_s_setprio(1);
#pragma unroll
        for (int m = 0; m < 4; ++m)
#pragma unroll
          for (int n = 0; n < 4; ++n)
            acc[m][n] = __builtin_amdgcn_mfma_f32_16x16x32_bf16(af[m], bfr[n], acc[m][n], 0, 0, 0);
        __builtin_amdgcn_s_setprio(0);
      }

      // 3. end-of-tap sync
      if (tap == 8) {
        __builtin_amdgcn_s_barrier();          // all waves done reading X[cs]
        if (cs < 7) stageX(cs + 1);
        asm volatile("s_waitcnt vmcnt(0)" ::: "memory");
        __builtin_amdgcn_s_barrier();
      } else {
        if (cs == 7 && tap == 7)               // no W[T+2] was issued
          asm volatile("s_waitcnt vmcnt(0)" ::: "memory");
        else                                    // W[T+1] done, W[T+2] in flight
          asm volatile("s_waitcnt vmcnt(4)" ::: "memory");
        __builtin_amdgcn_s_barrier();
      }
    }
  }

  // epilogue: D layout col=lane&15 (p), row=(lane>>4)*4+j (o)
#pragma unroll
  for (int m = 0; m < 4; ++m) {
    int o = o0 + wr * 64 + m * 16 + ((lane >> 4) << 2);
#pragma unroll
    for (int n = 0; n < 4; ++n) {
      int p = ptile * 128 + wc * 64 + n * 16 + (lane & 15);
      float* dst = out + ((size_t)b * 512 + o) * 4096 + p;
#pragma unroll
      for (int j = 0; j < 4; ++j) dst[(size_t)j * 4096] = acc[m][n][j];
    }
  }
}

// ---------------- launch --------------------------------------------------
extern "C" void kernel_launch(void* const* d_in, const int* in_sizes, int n_in,
                              void* d_out, int out_size, void* d_ws, size_t ws_size,
                              hipStream_t stream) {
  const float* x      = (const float*)d_in[0];
  const float* style  = (const float*)d_in[1];
  const float* weight = (const float*)d_in[2];
  const float* mod_w  = (const float*)d_in[3];
  float* out = (float*)d_out;

  __hip_bfloat16* xbf  = (__hip_bfloat16*)d_ws;                       // 33.55 MB
  __hip_bfloat16* wmod = (__hip_bfloat16*)((char*)d_ws + (size_t)8 * 4096 * 512 * 2);
  // s[8][512] is parked at the START of d_out: prep_kernel consumes it and
  // conv_kernel (which runs after) fully overwrites d_out.
  float* s_buf = (float*)d_out;

  style_kernel<<<dim3(128, 8), 256, 0, stream>>>(style, mod_w, s_buf);
  prep_kernel <<<dim3(4608), 256, 0, stream>>>(weight, s_buf, x, xbf, wmod);
  conv_kernel <<<dim3(1024), 256, 0, stream>>>(xbf, wmod, out);
}